// Round 1
// baseline (258.720 us; speedup 1.0000x reference)
//
#include <hip/hip_runtime.h>
#include <math.h>

#define B_ 16
#define C_ 64
#define H_ 256
#define W_ 256
#define HW_ 65536

__device__ __forceinline__ float waveSum(float v) {
#pragma unroll
    for (int o = 32; o > 0; o >>= 1) v += __shfl_down(v, o, 64);
    return v;
}
__device__ __forceinline__ float waveMax(float v) {
#pragma unroll
    for (int o = 32; o > 0; o >>= 1) v = fmaxf(v, __shfl_down(v, o, 64));
    return v;
}

// K1: per-(b,c) spatial sum and max of `weight`. grid=1024 blocks, 256 thr.
__global__ void reduce_weight(const float* __restrict__ w,
                              float* __restrict__ wsum, float* __restrict__ wmax) {
    int bc = blockIdx.x;
    const float4* p = (const float4*)(w + (size_t)bc * HW_);
    float s = 0.f, m = -INFINITY;
    for (int i = threadIdx.x; i < HW_ / 4; i += 256) {
        float4 v = p[i];
        s += v.x + v.y + v.z + v.w;
        m = fmaxf(m, fmaxf(fmaxf(v.x, v.y), fmaxf(v.z, v.w)));
    }
    __shared__ float ts[4], tm[4];
    int wid = threadIdx.x >> 6, lane = threadIdx.x & 63;
    s = waveSum(s);
    m = waveMax(m);
    if (lane == 0) { ts[wid] = s; tm[wid] = m; }
    __syncthreads();
    if (threadIdx.x == 0) {
        wsum[bc] = ts[0] + ts[1] + ts[2] + ts[3];
        wmax[bc] = fmaxf(fmaxf(tm[0], tm[1]), fmaxf(tm[2], tm[3]));
    }
}

// K2: channel attention MLP. grid=16 blocks (b), 64 threads.
__global__ void channel_attn(const float* __restrict__ wsum, const float* __restrict__ wmax,
                             const float* __restrict__ fc1, const float* __restrict__ fc2,
                             float* __restrict__ ca) {
    int b = blockIdx.x, t = threadIdx.x;
    __shared__ float ha[8], hm[8];
    if (t < 8) {
        float sa_ = 0.f, sm_ = 0.f;
        for (int c = 0; c < 64; ++c) {
            float f = fc1[t * 64 + c];
            sa_ += f * (wsum[b * 64 + c] * (1.f / (float)HW_));
            sm_ += f * wmax[b * 64 + c];
        }
        ha[t] = fmaxf(sa_, 0.f);
        hm[t] = fmaxf(sm_, 0.f);
    }
    __syncthreads();
    float o = 0.f;
#pragma unroll
    for (int j = 0; j < 8; ++j) o += (ha[j] + hm[j]) * fc2[t * 8 + j];
    ca[b * 64 + t] = 1.f / (1.f + expf(-o));
}

// K3: per-pixel channel mean & max of ca*weight. grid=(64,16), 256 thr, float4 pixels.
__global__ void spatial_stats(const float* __restrict__ w, const float* __restrict__ ca,
                              float* __restrict__ spm, float* __restrict__ spx) {
    int b = blockIdx.y;
    int pix4 = blockIdx.x * 256 + threadIdx.x;  // float4 index in plane (HW/4)
    __shared__ float cas[64];
    if (threadIdx.x < 64) cas[threadIdx.x] = ca[b * 64 + threadIdx.x];
    __syncthreads();
    const float4* base = (const float4*)(w + (size_t)b * 64 * HW_);
    float4 s = make_float4(0.f, 0.f, 0.f, 0.f);
    float4 m = make_float4(-INFINITY, -INFINITY, -INFINITY, -INFINITY);
#pragma unroll 8
    for (int c = 0; c < 64; ++c) {
        float4 v = base[(size_t)c * (HW_ / 4) + pix4];
        float a = cas[c];
        float vx = a * v.x, vy = a * v.y, vz = a * v.z, vw = a * v.w;
        s.x += vx; s.y += vy; s.z += vz; s.w += vw;
        m.x = fmaxf(m.x, vx); m.y = fmaxf(m.y, vy);
        m.z = fmaxf(m.z, vz); m.w = fmaxf(m.w, vw);
    }
    const float inv = 1.f / 64.f;
    float4 so = make_float4(s.x * inv, s.y * inv, s.z * inv, s.w * inv);
    ((float4*)spm)[(size_t)b * (HW_ / 4) + pix4] = so;
    ((float4*)spx)[(size_t)b * (HW_ / 4) + pix4] = m;
}

// K4: 7x7 conv over [mean,max] -> sigmoid. grid=(256,16), 256 thr (one row).
__global__ void sa_conv(const float* __restrict__ spm, const float* __restrict__ spx,
                        const float* __restrict__ sw, float* __restrict__ sa) {
    int b = blockIdx.y, y = blockIdx.x, x = threadIdx.x;
    const float* in0 = spm + (size_t)b * HW_;
    const float* in1 = spx + (size_t)b * HW_;
    float acc = 0.f;
#pragma unroll
    for (int ky = 0; ky < 7; ++ky) {
        int yy = y + ky - 3;
        if (yy < 0 || yy >= H_) continue;
        const float* r0 = in0 + yy * W_;
        const float* r1 = in1 + yy * W_;
#pragma unroll
        for (int kx = 0; kx < 7; ++kx) {
            int xx = x + kx - 3;
            if (xx < 0 || xx >= W_) continue;
            acc += r0[xx] * sw[ky * 7 + kx] + r1[xx] * sw[49 + ky * 7 + kx];
        }
    }
    sa[(size_t)b * HW_ + y * W_ + x] = 1.f / (1.f + expf(-acc));
}

// K5: s[b,c] = mean_hw(sa * weight). grid=1024, 256 thr.
__global__ void weighted_reduce(const float* __restrict__ w, const float* __restrict__ sa,
                                float* __restrict__ sval) {
    int bc = blockIdx.x;
    int b = bc >> 6;
    const float4* wp = (const float4*)(w + (size_t)bc * HW_);
    const float4* sp = (const float4*)(sa + (size_t)b * HW_);
    float s = 0.f;
    for (int i = threadIdx.x; i < HW_ / 4; i += 256) {
        float4 v = wp[i], q = sp[i];
        s += v.x * q.x + v.y * q.y + v.z * q.z + v.w * q.w;
    }
    __shared__ float ts[4];
    int wid = threadIdx.x >> 6, lane = threadIdx.x & 63;
    s = waveSum(s);
    if (lane == 0) ts[wid] = s;
    __syncthreads();
    if (threadIdx.x == 0)
        sval[bc] = (ts[0] + ts[1] + ts[2] + ts[3]) * (1.f / (float)HW_);
}

// K6: build per-sample 3x3 kernels. grid=16 (b), 64 thr (ic).
__global__ void make_kernel(const float* __restrict__ ca, const float* __restrict__ sval,
                            const float* __restrict__ pk1w, const float* __restrict__ pk1b,
                            const float* __restrict__ pk2w, const float* __restrict__ pk2b,
                            float* __restrict__ kern) {
    int b = blockIdx.x, o = threadIdx.x;
    __shared__ float wg[64];
    wg[o] = ca[b * 64 + o] * sval[b * 64 + o];
    __syncthreads();
    float p = pk1b[o];
#pragma unroll 8
    for (int c = 0; c < 64; ++c) p += pk1w[o * 64 + c] * wg[c];
#pragma unroll
    for (int j = 0; j < 9; ++j)
        kern[(b * 64 + o) * 9 + j] = p * pk2w[o * 9 + j] + pk2b[o * 9 + j];
}

// K7: per-sample 3x3x64 conv over x1. grid=512 (16 b x 32 tiles of 8 rows), 256 thr.
__global__ void final_conv(const float* __restrict__ x1, const float* __restrict__ kern,
                           float* __restrict__ out) {
    int gid = blockIdx.x;
    int b = gid >> 5;
    int y0 = (gid & 31) * 8;
    int x = threadIdx.x;
    float acc[8];
#pragma unroll
    for (int r = 0; r < 8; ++r) acc[r] = 0.f;

    for (int ic = 0; ic < 64; ++ic) {
        const float* plane = x1 + ((size_t)(b * 64 + ic) << 16);
        const float* kv = kern + (b * 64 + ic) * 9;
        float k0 = kv[0], k1 = kv[1], k2 = kv[2];
        float k3 = kv[3], k4 = kv[4], k5 = kv[5];
        float k6 = kv[6], k7 = kv[7], k8 = kv[8];
#pragma unroll
        for (int j = -1; j <= 8; ++j) {
            int yy = y0 + j;
            float m = 0.f, z = 0.f, p = 0.f;
            if (yy >= 0 && yy < H_) {
                const float* row = plane + yy * W_;
                z = row[x];
                m = (x > 0) ? row[x - 1] : 0.f;
                p = (x < W_ - 1) ? row[x + 1] : 0.f;
            }
            if (j + 1 <= 7) acc[j + 1] += m * k0 + z * k1 + p * k2;
            if (j >= 0 && j <= 7) acc[j] += m * k3 + z * k4 + p * k5;
            if (j - 1 >= 0) acc[j - 1] += m * k6 + z * k7 + p * k8;
        }
    }
#pragma unroll
    for (int r = 0; r < 8; ++r)
        out[(size_t)b * HW_ + (size_t)(y0 + r) * W_ + x] = acc[r];
}

extern "C" void kernel_launch(void* const* d_in, const int* in_sizes, int n_in,
                              void* d_out, int out_size, void* d_ws, size_t ws_size,
                              hipStream_t stream) {
    const float* x1     = (const float*)d_in[0];
    const float* weight = (const float*)d_in[1];
    const float* fc1    = (const float*)d_in[2];
    const float* fc2    = (const float*)d_in[3];
    const float* saw    = (const float*)d_in[4];
    const float* pk1w   = (const float*)d_in[5];
    const float* pk1b   = (const float*)d_in[6];
    const float* pk2w   = (const float*)d_in[7];
    const float* pk2b   = (const float*)d_in[8];
    float* out = (float*)d_out;

    float* ws   = (float*)d_ws;
    float* wsum = ws;                 // 1024
    float* wmax = ws + 1024;          // 1024
    float* ca   = ws + 2048;          // 1024
    float* sval = ws + 3072;          // 1024
    float* kern = ws + 4096;          // 9216
    float* spm  = ws + 16384;         // 1048576
    float* spx  = spm + (size_t)B_ * HW_;
    float* sa   = spx + (size_t)B_ * HW_;

    reduce_weight<<<dim3(B_ * C_), 256, 0, stream>>>(weight, wsum, wmax);
    channel_attn<<<dim3(B_), 64, 0, stream>>>(wsum, wmax, fc1, fc2, ca);
    spatial_stats<<<dim3(HW_ / 4 / 256, B_), 256, 0, stream>>>(weight, ca, spm, spx);
    sa_conv<<<dim3(H_, B_), 256, 0, stream>>>(spm, spx, saw, sa);
    weighted_reduce<<<dim3(B_ * C_), 256, 0, stream>>>(weight, sa, sval);
    make_kernel<<<dim3(B_), 64, 0, stream>>>(ca, sval, pk1w, pk1b, pk2w, pk2b, kern);
    final_conv<<<dim3(B_ * 32), 256, 0, stream>>>(x1, kern, out);
}